// Round 2
// baseline (50349.814 us; speedup 1.0000x reference)
//
#include <hip/hip_runtime.h>

#define S_LEN 8192
#define KREL 8
#define WPD 32   // workgroups per direction; each owns 512/WPD = 16 h-columns

__device__ __forceinline__ float sigmf(float x) { return 1.0f / (1.0f + __expf(-x)); }
// exact rearrangement of (e^2x-1)/(e^2x+1); saturates correctly at +/-inf
__device__ __forceinline__ float tanhfast(float x) { return 1.0f - 2.0f / (__expf(2.0f * x) + 1.0f); }

// ---------------- mask canonicalization ----------------
// The harness may hand us jnp bool masks as int8, int32, or float32.
// Detect from the first 1024 aligned words (safe: smallest candidate buffer
// is n bytes = 65536) and write canonical uint8 0/1.
//   all words in {0,1}          -> int32
//   all words in {0,0x3F800000} -> float32
//   else                        -> bytes (int8/bool)
// Bool data (60% true) matches the int32 pattern with prob 0.4^3072 ~ 0.
__global__ void k_maskcvt(const unsigned char* __restrict__ src,
                          unsigned char* __restrict__ dst, int n)
{
  const unsigned int* w = (const unsigned int*)src;
  __shared__ int s_i32, s_f32;
  if (threadIdx.x == 0) { s_i32 = 1; s_f32 = 1; }
  __syncthreads();
  int i32ok = 1, f32ok = 1;
  for (int i = threadIdx.x; i < 1024; i += blockDim.x) {
    const unsigned int v = w[i];
    if (v != 0u && v != 1u) i32ok = 0;
    if (v != 0u && v != 0x3F800000u) f32ok = 0;
  }
  if (!i32ok) atomicAnd(&s_i32, 0);
  if (!f32ok) atomicAnd(&s_f32, 0);
  __syncthreads();
  const int wide = (s_i32 || s_f32);   // 4-byte elements (0 is falsy either way)
  for (int i = blockIdx.x * blockDim.x + threadIdx.x; i < n; i += gridDim.x * blockDim.x)
    dst[i] = wide ? (w[i] ? 1 : 0) : (src[i] ? 1 : 0);
}

// ---------------- parallel precompute ----------------
// P[t][r] = X[t] . Wrow[r] + bias[r], r in [0,3072)
//   r in [0,2560)  : Wioux row r,       bias = bioux[r] + biouh[r]   (both biases folded)
//   r in [2560,..) : Wlx row r-2560,    bias = blx[.] + blh[.]       (blh folded too)
__global__ __launch_bounds__(256)
void k_gemm(const float* __restrict__ X, const float* __restrict__ Wioux,
            const float* __restrict__ Wlx, const float* __restrict__ bioux,
            const float* __restrict__ biouh, const float* __restrict__ blx,
            const float* __restrict__ blh, float* __restrict__ P)
{
  __shared__ float As[16][64];   // [k][t] transposed so compute reads are contiguous float4
  __shared__ float Bs[16][64];   // [k][r]
  const int t0 = blockIdx.x * 64;
  const int r0 = blockIdx.y * 64;
  const int tid = threadIdx.x;
  const int tx = tid & 15, ty = tid >> 4;
  const int si = tid >> 2, sk = (tid & 3) << 2;
  const int rB = r0 + si;
  const float* brow = (rB < 2560) ? (Wioux + (size_t)rB * 512)
                                  : (Wlx + (size_t)(rB - 2560) * 512);
  const float* arow = X + (size_t)(t0 + si) * 512;
  float acc[4][4] = {};
  for (int k0 = 0; k0 < 512; k0 += 16) {
    const float4 av = *(const float4*)(arow + k0 + sk);
    const float4 bv = *(const float4*)(brow + k0 + sk);
    __syncthreads();
    As[sk + 0][si] = av.x; As[sk + 1][si] = av.y; As[sk + 2][si] = av.z; As[sk + 3][si] = av.w;
    Bs[sk + 0][si] = bv.x; Bs[sk + 1][si] = bv.y; Bs[sk + 2][si] = bv.z; Bs[sk + 3][si] = bv.w;
    __syncthreads();
#pragma unroll
    for (int kk = 0; kk < 16; ++kk) {
      const float4 a = *(const float4*)&As[kk][ty * 4];
      const float4 b = *(const float4*)&Bs[kk][tx * 4];
      acc[0][0] += a.x * b.x; acc[0][1] += a.x * b.y; acc[0][2] += a.x * b.z; acc[0][3] += a.x * b.w;
      acc[1][0] += a.y * b.x; acc[1][1] += a.y * b.y; acc[1][2] += a.y * b.z; acc[1][3] += a.y * b.w;
      acc[2][0] += a.z * b.x; acc[2][1] += a.z * b.y; acc[2][2] += a.z * b.z; acc[2][3] += a.z * b.w;
      acc[3][0] += a.w * b.x; acc[3][1] += a.w * b.y; acc[3][2] += a.w * b.z; acc[3][3] += a.w * b.w;
    }
  }
#pragma unroll
  for (int i = 0; i < 4; ++i) {
    const int t = t0 + ty * 4 + i;
#pragma unroll
    for (int j = 0; j < 4; ++j) {
      const int r = r0 + tx * 4 + j;
      const float bias = (r < 2560) ? (bioux[r] + biouh[r]) : (blx[r - 2560] + blh[r - 2560]);
      P[(size_t)t * 3072 + r] = acc[i][j] + bias;
    }
  }
}

// ---------------- persistent recurrent kernel ----------------
// 64 WGs: wg<32 forward, wg>=32 backward. Each WG owns h-columns [w*16, w*16+16)
// and keeps its 96 weight rows (5 Wiouh chunks + Wlh) in VGPRs: 192 floats/thread.
// Cross-WG data per step: only the 512-float h vector (double-buffered, agent-scope).
// G[j]=Wlh@h_j and the output rows are written & read by the SAME thread (column owner),
// so plain loads/stores are safe (same CU, same L1).
__global__ __launch_bounds__(256, 1)
void k_rec(const float* __restrict__ Wiouh, const float* __restrict__ Wlh,
           const float* __restrict__ P, const float* __restrict__ lb,
           const int* __restrict__ rel_fw, const int* __restrict__ dep_fw,
           const unsigned char* __restrict__ mask_fw,
           const int* __restrict__ rel_bw, const int* __restrict__ dep_bw,
           const unsigned char* __restrict__ mask_bw,
           float* __restrict__ Gfw, float* __restrict__ Gbw,
           float* hbuf, int* flags, float* __restrict__ out)
{
  const int wg  = blockIdx.x;
  const int dir = wg / WPD;            // 0 fw, 1 bw
  const int w   = wg % WPD;
  const int tid = threadIdx.x;
  const int grp = tid >> 4;            // 16 column-groups per WG
  const int lane = tid & 15;           // 16 lanes share one column's dot products
  const int m = w * 16 + grp;          // owned h-column, 0..511
  const int dircol = dir * 512;
  const int* rel = dir ? rel_bw : rel_fw;
  const int* dep = dir ? dep_bw : dep_fw;
  const unsigned char* msk = dir ? mask_bw : mask_fw;
  float* Gbuf = dir ? Gbw : Gfw;

  // ---- weights into registers: 6 rows x 32 cols each (cols = lane*4 + 64*q) ----
  float4 wreg[6][8];
  {
    const float* rows[6];
#pragma unroll
    for (int rg = 0; rg < 5; ++rg) rows[rg] = Wiouh + (size_t)(rg * 512 + m) * 512;
    rows[5] = Wlh + (size_t)m * 512;
#pragma unroll
    for (int rg = 0; rg < 6; ++rg)
#pragma unroll
      for (int q = 0; q < 8; ++q)
        wreg[rg][q] = *(const float4*)(rows[rg] + lane * 4 + 64 * q);
  }

  __shared__ float hs[512];
  hs[tid] = 0.0f; hs[tid + 256] = 0.0f;
  __syncthreads();

  float cstate = 0.0f;

#pragma unroll 1
  for (int s = 0; s < S_LEN; ++s) {
    const int t = dir ? (S_LEN - 1 - s) : s;
    const int prevt = dir ? (t + 1) : (t - 1);   // valid only for s>0

    // ---- prefetch gathers + P row (column owners only); overlaps with dots ----
    int jj[KREL]; int mk[KREL];
    float Hg[KREL], Gg[KREL], LBg[KREL];
    float p0, p1, p2, p3, p4, p5;
    if (lane == 0) {
      const int tb = t * KREL;
#pragma unroll
      for (int k = 0; k < KREL; ++k) { jj[k] = rel[tb + k]; mk[k] = (int)msk[tb + k]; }
#pragma unroll
      for (int k = 0; k < KREL; ++k) Hg[k] = out[(size_t)jj[k] * 1024 + dircol + m];
#pragma unroll
      for (int k = 0; k < KREL; ++k) Gg[k] = Gbuf[(size_t)jj[k] * 512 + m];
#pragma unroll
      for (int k = 0; k < KREL; ++k) LBg[k] = lb[(size_t)dep[tb + k] * 512 + m];
      const float* prow = P + (size_t)t * 3072;
      p0 = prow[m];        p1 = prow[512 + m];  p2 = prow[1024 + m];
      p3 = prow[1536 + m]; p4 = prow[2048 + m]; p5 = prow[2560 + m];
    }

    // ---- recurrent dots: [Wiouh;Wlh] @ h_prev for 6 owned rows ----
    float4 h4[8];
#pragma unroll
    for (int q = 0; q < 8; ++q) h4[q] = *(const float4*)&hs[lane * 4 + 64 * q];
    float dsum[6];
#pragma unroll
    for (int rg = 0; rg < 6; ++rg) {
      float a = 0.0f;
#pragma unroll
      for (int q = 0; q < 8; ++q) {
        a += wreg[rg][q].x * h4[q].x;
        a += wreg[rg][q].y * h4[q].y;
        a += wreg[rg][q].z * h4[q].z;
        a += wreg[rg][q].w * h4[q].w;
      }
      a += __shfl_xor(a, 1); a += __shfl_xor(a, 2);
      a += __shfl_xor(a, 4); a += __shfl_xor(a, 8);
      dsum[rg] = a;
    }

    // ---- gates + gather combine (column owners) ----
    if (lane == 0) {
      // faithful gate order: i=sig(c0), o=sig(c1), s=sig(c2), f=sig(c3), u=tanh(c4)
      const float iv = sigmf(p0 + dsum[0]);
      const float ov = sigmf(p1 + dsum[1]);
      const float sv = sigmf(p2 + dsum[2]);
      const float fv = sigmf(p3 + dsum[3]);
      const float uv = tanhfast(p4 + dsum[4]);
      cstate = fv * cstate + iv * uv;
      const float hb = ov * tanhfast(cstate);
      const float g = dsum[5];                       // Wlh @ h_prev, column m
      if (s > 0) Gbuf[(size_t)prevt * 512 + m] = g;  // publish G for prev timestep
      float agg = 0.0f;
#pragma unroll
      for (int k = 0; k < KREL; ++k) {
        if (mk[k]) {
          const float gv = (s > 0 && jj[k] == prevt) ? g : Gg[k];
          agg += sigmf(gv + p5 + LBg[k]) * Hg[k];
        }
      }
      const float hval = hb + sv * tanhfast(agg);
      out[(size_t)t * 1024 + dircol + m] = hval;     // output + future gathers (same thread)
      __hip_atomic_store(&hbuf[((s & 1) * 2 + dir) * 512 + m], hval,
                         __ATOMIC_RELAXED, __HIP_MEMORY_SCOPE_AGENT);
    }
    __syncthreads();   // vmcnt(0) drain: all h stores at coherent point before flag

    if (s < S_LEN - 1) {
      if (tid == 0)
        __hip_atomic_store(&flags[dir * WPD + w], s + 1,
                           __ATOMIC_RELEASE, __HIP_MEMORY_SCOPE_AGENT);
      if (tid < WPD) {   // 32 threads each poll one producer flag (no RMW contention)
        while (__hip_atomic_load(&flags[dir * WPD + tid],
                                 __ATOMIC_RELAXED, __HIP_MEMORY_SCOPE_AGENT) < s + 1) {}
      }
      __syncthreads();
      const float* hsrc = hbuf + ((s & 1) * 2 + dir) * 512;
      hs[tid]       = __hip_atomic_load(&hsrc[tid],       __ATOMIC_RELAXED, __HIP_MEMORY_SCOPE_AGENT);
      hs[tid + 256] = __hip_atomic_load(&hsrc[tid + 256], __ATOMIC_RELAXED, __HIP_MEMORY_SCOPE_AGENT);
      __syncthreads();
    }
  }
}

__global__ void k_fill(float* __restrict__ o, int n, float v)
{ const int i = blockIdx.x * 256 + threadIdx.x; if (i < n) o[i] = v; }

extern "C" void kernel_launch(void* const* d_in, const int* in_sizes, int n_in,
                              void* d_out, int out_size, void* d_ws, size_t ws_size,
                              hipStream_t stream)
{
  (void)in_sizes; (void)n_in;
  const float* X     = (const float*)d_in[0];
  const float* Wioux = (const float*)d_in[1];
  const float* bioux = (const float*)d_in[2];
  const float* Wiouh = (const float*)d_in[3];
  const float* biouh = (const float*)d_in[4];
  const float* Wlx   = (const float*)d_in[5];
  const float* blx   = (const float*)d_in[6];
  const float* Wlh   = (const float*)d_in[7];
  const float* blh   = (const float*)d_in[8];
  const float* lb    = (const float*)d_in[9];
  const int* rel_fw  = (const int*)d_in[10];
  const int* dep_fw  = (const int*)d_in[11];
  const unsigned char* mask_fw_raw = (const unsigned char*)d_in[12];
  const int* rel_bw  = (const int*)d_in[13];
  const int* dep_bw  = (const int*)d_in[14];
  const unsigned char* mask_bw_raw = (const unsigned char*)d_in[15];
  float* out = (float*)d_out;

  const int nmask = S_LEN * KREL;                  // 65536
  const size_t needP = (size_t)S_LEN * 3072 * 4;   // 96 MB
  const size_t needG = (size_t)S_LEN * 512 * 4;    // 16 MB each
  const size_t need  = 16384 + needP + 2 * needG + 2 * (size_t)nmask;
  if (ws_size < need) {
    // distinctive sentinel so a ws-size failure is distinguishable from a math bug
    k_fill<<<(out_size + 255) / 256, 256, 0, stream>>>(out, out_size, 12345.0f);
    return;
  }
  char* ws = (char*)d_ws;
  int*   flags = (int*)ws;                 // 2*32 ints, zeroed below
  float* hbuf  = (float*)(ws + 8192);      // [2 bufs][2 dir][512]
  float* P     = (float*)(ws + 16384);     // [8192][3072]
  float* Gfw   = (float*)(ws + 16384 + needP);
  float* Gbw   = Gfw + (size_t)S_LEN * 512;
  unsigned char* Mfw = (unsigned char*)(ws + 16384 + needP + 2 * needG);
  unsigned char* Mbw = Mfw + nmask;

  hipMemsetAsync(flags, 0, 1024, stream);
  k_maskcvt<<<64, 256, 0, stream>>>(mask_fw_raw, Mfw, nmask);
  k_maskcvt<<<64, 256, 0, stream>>>(mask_bw_raw, Mbw, nmask);
  dim3 gg(S_LEN / 64, 3072 / 64);
  k_gemm<<<gg, 256, 0, stream>>>(X, Wioux, Wlx, bioux, biouh, blx, blh, P);
  k_rec<<<2 * WPD, 256, 0, stream>>>(Wiouh, Wlh, P, lb, rel_fw, dep_fw, Mfw,
                                     rel_bw, dep_bw, Mbw, Gfw, Gbw, hbuf, flags, out);
}

// Round 3
// 39206.143 us; speedup vs baseline: 1.2842x; 1.2842x over previous
//
#include <hip/hip_runtime.h>

#define S_LEN 8192
#define KREL 8
#define WPD 32   // workgroups per direction; each owns 512/WPD = 16 h-columns

__device__ __forceinline__ float sigmf(float x) { return 1.0f / (1.0f + __expf(-x)); }
__device__ __forceinline__ float tanhfast(float x) { return 1.0f - 2.0f / (__expf(2.0f * x) + 1.0f); }

// ---------------- mask canonicalization (unchanged, R2-verified) ----------------
__global__ void k_maskcvt(const unsigned char* __restrict__ src,
                          unsigned char* __restrict__ dst, int n)
{
  const unsigned int* w = (const unsigned int*)src;
  __shared__ int s_i32, s_f32;
  if (threadIdx.x == 0) { s_i32 = 1; s_f32 = 1; }
  __syncthreads();
  int i32ok = 1, f32ok = 1;
  for (int i = threadIdx.x; i < 1024; i += blockDim.x) {
    const unsigned int v = w[i];
    if (v != 0u && v != 1u) i32ok = 0;
    if (v != 0u && v != 0x3F800000u) f32ok = 0;
  }
  if (!i32ok) atomicAnd(&s_i32, 0);
  if (!f32ok) atomicAnd(&s_f32, 0);
  __syncthreads();
  const int wide = (s_i32 || s_f32);
  for (int i = blockIdx.x * blockDim.x + threadIdx.x; i < n; i += gridDim.x * blockDim.x)
    dst[i] = wide ? (w[i] ? 1 : 0) : (src[i] ? 1 : 0);
}

// ---------------- parallel precompute (unchanged, R2-verified) ----------------
__global__ __launch_bounds__(256)
void k_gemm(const float* __restrict__ X, const float* __restrict__ Wioux,
            const float* __restrict__ Wlx, const float* __restrict__ bioux,
            const float* __restrict__ biouh, const float* __restrict__ blx,
            const float* __restrict__ blh, float* __restrict__ P)
{
  __shared__ float As[16][64];
  __shared__ float Bs[16][64];
  const int t0 = blockIdx.x * 64;
  const int r0 = blockIdx.y * 64;
  const int tid = threadIdx.x;
  const int tx = tid & 15, ty = tid >> 4;
  const int si = tid >> 2, sk = (tid & 3) << 2;
  const int rB = r0 + si;
  const float* brow = (rB < 2560) ? (Wioux + (size_t)rB * 512)
                                  : (Wlx + (size_t)(rB - 2560) * 512);
  const float* arow = X + (size_t)(t0 + si) * 512;
  float acc[4][4] = {};
  for (int k0 = 0; k0 < 512; k0 += 16) {
    const float4 av = *(const float4*)(arow + k0 + sk);
    const float4 bv = *(const float4*)(brow + k0 + sk);
    __syncthreads();
    As[sk + 0][si] = av.x; As[sk + 1][si] = av.y; As[sk + 2][si] = av.z; As[sk + 3][si] = av.w;
    Bs[sk + 0][si] = bv.x; Bs[sk + 1][si] = bv.y; Bs[sk + 2][si] = bv.z; Bs[sk + 3][si] = bv.w;
    __syncthreads();
#pragma unroll
    for (int kk = 0; kk < 16; ++kk) {
      const float4 a = *(const float4*)&As[kk][ty * 4];
      const float4 b = *(const float4*)&Bs[kk][tx * 4];
      acc[0][0] += a.x * b.x; acc[0][1] += a.x * b.y; acc[0][2] += a.x * b.z; acc[0][3] += a.x * b.w;
      acc[1][0] += a.y * b.x; acc[1][1] += a.y * b.y; acc[1][2] += a.y * b.z; acc[1][3] += a.y * b.w;
      acc[2][0] += a.z * b.x; acc[2][1] += a.z * b.y; acc[2][2] += a.z * b.z; acc[2][3] += a.z * b.w;
      acc[3][0] += a.w * b.x; acc[3][1] += a.w * b.y; acc[3][2] += a.w * b.z; acc[3][3] += a.w * b.w;
    }
  }
#pragma unroll
  for (int i = 0; i < 4; ++i) {
    const int t = t0 + ty * 4 + i;
#pragma unroll
    for (int j = 0; j < 4; ++j) {
      const int r = r0 + tx * 4 + j;
      const float bias = (r < 2560) ? (bioux[r] + biouh[r]) : (blx[r - 2560] + blh[r - 2560]);
      P[(size_t)t * 3072 + r] = acc[i][j] + bias;
    }
  }
}

// ---------------- persistent recurrent kernel ----------------
// Sync protocol v2: per-(dir,column) 64-bit records {h:f32, tag:u32}, double-buffered
// by step parity. ONE relaxed agent atomic store publishes h; consumers poll the
// packet itself (tag >= s). Packet atomicity replaces all release/acquire fencing.
// Lag<=2 proof: storing tag s+3 into a slot requires having consumed tag s+2 from
// all WGs, which requires those WGs consumed tag s+1 -> slot free to overwrite.
// Gathers for step s+1 are prefetched at end of step s; rows stored this step
// (out[t], Gbuf[prevt]) are patched from registers, older rows crossed >=1
// vmcnt-draining barrier so same-CU loads are safe.
__global__ __launch_bounds__(256, 1)
void k_rec(const float* __restrict__ Wiouh, const float* __restrict__ Wlh,
           const float* __restrict__ P, const float* __restrict__ lb,
           const int* __restrict__ rel_fw, const int* __restrict__ dep_fw,
           const unsigned char* __restrict__ mask_fw,
           const int* __restrict__ rel_bw, const int* __restrict__ dep_bw,
           const unsigned char* __restrict__ mask_bw,
           float* __restrict__ Gfw, float* __restrict__ Gbw,
           unsigned long long* rec, float* __restrict__ out)
{
  const int wg  = blockIdx.x;
  const int dir = wg / WPD;
  const int w   = wg % WPD;
  const int tid = threadIdx.x;
  const int grp = tid >> 4;
  const int lane = tid & 15;
  const int m = w * 16 + grp;
  const int dircol = dir * 512;
  const int* rel = dir ? rel_bw : rel_fw;
  const int* dep = dir ? dep_bw : dep_fw;
  const unsigned char* msk = dir ? mask_bw : mask_fw;
  float* Gbuf = dir ? Gbw : Gfw;

  // ---- weights into registers: 6 rows x 32 cols each ----
  float4 wreg[6][8];
  {
    const float* rows[6];
#pragma unroll
    for (int rg = 0; rg < 5; ++rg) rows[rg] = Wiouh + (size_t)(rg * 512 + m) * 512;
    rows[5] = Wlh + (size_t)m * 512;
#pragma unroll
    for (int rg = 0; rg < 6; ++rg)
#pragma unroll
      for (int q = 0; q < 8; ++q)
        wreg[rg][q] = *(const float4*)(rows[rg] + lane * 4 + 64 * q);
  }

  __shared__ float hs[2][512];
  hs[0][tid] = 0.0f; hs[0][tid + 256] = 0.0f;

  float cstate = 0.0f;

  // ---- prefetch state for the CURRENT step (lane0 threads only) ----
  int jj[KREL]; int mk[KREL];
  float Hg[KREL], Gg[KREL], LBg[KREL];
  float p0, p1, p2, p3, p4, p5;
  if (lane == 0) {
    const int tf = dir ? (S_LEN - 1) : 0;
    const int tb = tf * KREL;
#pragma unroll
    for (int k = 0; k < KREL; ++k) { jj[k] = rel[tb + k]; mk[k] = (int)msk[tb + k]; }
    // first step's relatives are fully masked (reference guarantees); loads are dead
#pragma unroll
    for (int k = 0; k < KREL; ++k) Hg[k] = out[(size_t)jj[k] * 1024 + dircol + m];
#pragma unroll
    for (int k = 0; k < KREL; ++k) Gg[k] = Gbuf[(size_t)jj[k] * 512 + m];
#pragma unroll
    for (int k = 0; k < KREL; ++k) LBg[k] = lb[(size_t)dep[tb + k] * 512 + m];
    const float* prow = P + (size_t)tf * 3072;
    p0 = prow[m];        p1 = prow[512 + m];  p2 = prow[1024 + m];
    p3 = prow[1536 + m]; p4 = prow[2048 + m]; p5 = prow[2560 + m];
  }
  __syncthreads();

#pragma unroll 1
  for (int s = 0; s < S_LEN; ++s) {
    const int t = dir ? (S_LEN - 1 - s) : s;
    const int tn = dir ? (t - 1) : (t + 1);      // next step's t (valid if s<S_LEN-1)
    const int prevt = dir ? (t + 1) : (t - 1);   // valid only for s>0

    if (s > 0) {
      // ---- single-round-trip consume: poll the data packets directly ----
      const int pb = (((s - 1) & 1) * 2 + dir) * 512;
      unsigned long long v0, v1;
      do { v0 = __hip_atomic_load(rec + pb + tid, __ATOMIC_RELAXED, __HIP_MEMORY_SCOPE_AGENT); }
      while ((unsigned)(v0 >> 32) < (unsigned)s);
      do { v1 = __hip_atomic_load(rec + pb + tid + 256, __ATOMIC_RELAXED, __HIP_MEMORY_SCOPE_AGENT); }
      while ((unsigned)(v1 >> 32) < (unsigned)s);
      hs[s & 1][tid]       = __uint_as_float((unsigned)v0);
      hs[s & 1][tid + 256] = __uint_as_float((unsigned)v1);
      __syncthreads();   // the only barrier per step
    }

    // ---- recurrent dots: [Wiouh;Wlh] @ h_prev for 6 owned rows ----
    float4 h4[8];
#pragma unroll
    for (int q = 0; q < 8; ++q) h4[q] = *(const float4*)&hs[s & 1][lane * 4 + 64 * q];
    float dsum[6];
#pragma unroll
    for (int rg = 0; rg < 6; ++rg) {
      float a = 0.0f;
#pragma unroll
      for (int q = 0; q < 8; ++q) {
        a += wreg[rg][q].x * h4[q].x;
        a += wreg[rg][q].y * h4[q].y;
        a += wreg[rg][q].z * h4[q].z;
        a += wreg[rg][q].w * h4[q].w;
      }
      a += __shfl_xor(a, 1); a += __shfl_xor(a, 2);
      a += __shfl_xor(a, 4); a += __shfl_xor(a, 8);
      dsum[rg] = a;
    }

    if (lane == 0) {
      // faithful gate order: i=sig(c0), o=sig(c1), s=sig(c2), f=sig(c3), u=tanh(c4)
      const float iv = sigmf(p0 + dsum[0]);
      const float ov = sigmf(p1 + dsum[1]);
      const float sv = sigmf(p2 + dsum[2]);
      const float fv = sigmf(p3 + dsum[3]);
      const float uv = tanhfast(p4 + dsum[4]);
      cstate = fv * cstate + iv * uv;
      const float hb = ov * tanhfast(cstate);
      const float g = dsum[5];                       // Wlh @ h_prev = G[prevt]
      float agg = 0.0f;
#pragma unroll
      for (int k = 0; k < KREL; ++k) {
        if (mk[k]) {
          const float gv = (s > 0 && jj[k] == prevt) ? g : Gg[k];
          agg += sigmf(gv + p5 + LBg[k]) * Hg[k];
        }
      }
      const float hval = hb + sv * tanhfast(agg);

      // ---- publish FIRST (critical path): one relaxed 64-bit packet ----
      const unsigned long long pk =
          ((unsigned long long)(unsigned)(s + 1) << 32) | (unsigned long long)__float_as_uint(hval);
      __hip_atomic_store(rec + ((s & 1) * 2 + dir) * 512 + m, pk,
                         __ATOMIC_RELAXED, __HIP_MEMORY_SCOPE_AGENT);

      out[(size_t)t * 1024 + dircol + m] = hval;
      if (s > 0) Gbuf[(size_t)prevt * 512 + m] = g;

      // ---- prefetch next step's gathers (one step of slack to land) ----
      if (s < S_LEN - 1) {
        const int tb = tn * KREL;
#pragma unroll
        for (int k = 0; k < KREL; ++k) { jj[k] = rel[tb + k]; mk[k] = (int)msk[tb + k]; }
#pragma unroll
        for (int k = 0; k < KREL; ++k)
          Hg[k] = (jj[k] == t) ? hval : out[(size_t)jj[k] * 1024 + dircol + m];
#pragma unroll
        for (int k = 0; k < KREL; ++k)
          Gg[k] = (s > 0 && jj[k] == prevt) ? g : Gbuf[(size_t)jj[k] * 512 + m];
          // jj[k]==t (row not yet in Gbuf) is patched at use time next step (prevt'==t)
#pragma unroll
        for (int k = 0; k < KREL; ++k) LBg[k] = lb[(size_t)dep[tb + k] * 512 + m];
        const float* prow = P + (size_t)tn * 3072;
        p0 = prow[m];        p1 = prow[512 + m];  p2 = prow[1024 + m];
        p3 = prow[1536 + m]; p4 = prow[2048 + m]; p5 = prow[2560 + m];
      }
    }
  }
}

__global__ void k_fill(float* __restrict__ o, int n, float v)
{ const int i = blockIdx.x * 256 + threadIdx.x; if (i < n) o[i] = v; }

extern "C" void kernel_launch(void* const* d_in, const int* in_sizes, int n_in,
                              void* d_out, int out_size, void* d_ws, size_t ws_size,
                              hipStream_t stream)
{
  (void)in_sizes; (void)n_in;
  const float* X     = (const float*)d_in[0];
  const float* Wioux = (const float*)d_in[1];
  const float* bioux = (const float*)d_in[2];
  const float* Wiouh = (const float*)d_in[3];
  const float* biouh = (const float*)d_in[4];
  const float* Wlx   = (const float*)d_in[5];
  const float* blx   = (const float*)d_in[6];
  const float* Wlh   = (const float*)d_in[7];
  const float* blh   = (const float*)d_in[8];
  const float* lb    = (const float*)d_in[9];
  const int* rel_fw  = (const int*)d_in[10];
  const int* dep_fw  = (const int*)d_in[11];
  const unsigned char* mask_fw_raw = (const unsigned char*)d_in[12];
  const int* rel_bw  = (const int*)d_in[13];
  const int* dep_bw  = (const int*)d_in[14];
  const unsigned char* mask_bw_raw = (const unsigned char*)d_in[15];
  float* out = (float*)d_out;

  const int nmask = S_LEN * KREL;                  // 65536
  const size_t needP = (size_t)S_LEN * 3072 * 4;   // 96 MB
  const size_t needG = (size_t)S_LEN * 512 * 4;    // 16 MB each
  const size_t need  = 32768 + needP + 2 * needG + 2 * (size_t)nmask;
  if (ws_size < need) {
    k_fill<<<(out_size + 255) / 256, 256, 0, stream>>>(out, out_size, 12345.0f);
    return;
  }
  char* ws = (char*)d_ws;
  unsigned long long* rec = (unsigned long long*)ws;   // [2 buf][2 dir][512] packets, 16 KB
  float* P   = (float*)(ws + 32768);
  float* Gfw = (float*)(ws + 32768 + needP);
  float* Gbw = Gfw + (size_t)S_LEN * 512;
  unsigned char* Mfw = (unsigned char*)(ws + 32768 + needP + 2 * needG);
  unsigned char* Mbw = Mfw + nmask;

  hipMemsetAsync(rec, 0, 16384, stream);   // tags must start at 0 (ws is poisoned 0xAA)
  k_maskcvt<<<64, 256, 0, stream>>>(mask_fw_raw, Mfw, nmask);
  k_maskcvt<<<64, 256, 0, stream>>>(mask_bw_raw, Mbw, nmask);
  dim3 gg(S_LEN / 64, 3072 / 64);
  k_gemm<<<gg, 256, 0, stream>>>(X, Wioux, Wlx, bioux, biouh, blx, blh, P);
  k_rec<<<2 * WPD, 256, 0, stream>>>(Wiouh, Wlh, P, lb, rel_fw, dep_fw, Mfw,
                                     rel_bw, dep_bw, Mbw, Gfw, Gbw, rec, out);
}

// Round 4
// 22871.974 us; speedup vs baseline: 2.2014x; 1.7142x over previous
//
#include <hip/hip_runtime.h>

#define S_LEN 8192
#define KREL 8
#define WPD 64   // workgroups per direction; each owns 512/WPD = 8 h-columns

__device__ __forceinline__ float sigmf(float x) { return 1.0f / (1.0f + __expf(-x)); }
__device__ __forceinline__ float tanhfast(float x) { return 1.0f - 2.0f / (__expf(2.0f * x) + 1.0f); }

struct __attribute__((aligned(16))) F4 { float x, y, z, w; };

// ---------------- mask canonicalization (R2-verified) ----------------
__global__ void k_maskcvt(const unsigned char* __restrict__ src,
                          unsigned char* __restrict__ dst, int n)
{
  const unsigned int* w = (const unsigned int*)src;
  __shared__ int s_i32, s_f32;
  if (threadIdx.x == 0) { s_i32 = 1; s_f32 = 1; }
  __syncthreads();
  int i32ok = 1, f32ok = 1;
  for (int i = threadIdx.x; i < 1024; i += blockDim.x) {
    const unsigned int v = w[i];
    if (v != 0u && v != 1u) i32ok = 0;
    if (v != 0u && v != 0x3F800000u) f32ok = 0;
  }
  if (!i32ok) atomicAnd(&s_i32, 0);
  if (!f32ok) atomicAnd(&s_f32, 0);
  __syncthreads();
  const int wide = (s_i32 || s_f32);
  for (int i = blockIdx.x * blockDim.x + threadIdx.x; i < n; i += gridDim.x * blockDim.x)
    dst[i] = wide ? (w[i] ? 1 : 0) : (src[i] ? 1 : 0);
}

// ---------------- parallel precompute (R2-verified) ----------------
__global__ __launch_bounds__(256)
void k_gemm(const float* __restrict__ X, const float* __restrict__ Wioux,
            const float* __restrict__ Wlx, const float* __restrict__ bioux,
            const float* __restrict__ biouh, const float* __restrict__ blx,
            const float* __restrict__ blh, float* __restrict__ P)
{
  __shared__ float As[16][64];
  __shared__ float Bs[16][64];
  const int t0 = blockIdx.x * 64;
  const int r0 = blockIdx.y * 64;
  const int tid = threadIdx.x;
  const int tx = tid & 15, ty = tid >> 4;
  const int si = tid >> 2, sk = (tid & 3) << 2;
  const int rB = r0 + si;
  const float* brow = (rB < 2560) ? (Wioux + (size_t)rB * 512)
                                  : (Wlx + (size_t)(rB - 2560) * 512);
  const float* arow = X + (size_t)(t0 + si) * 512;
  float acc[4][4] = {};
  for (int k0 = 0; k0 < 512; k0 += 16) {
    const float4 av = *(const float4*)(arow + k0 + sk);
    const float4 bv = *(const float4*)(brow + k0 + sk);
    __syncthreads();
    As[sk + 0][si] = av.x; As[sk + 1][si] = av.y; As[sk + 2][si] = av.z; As[sk + 3][si] = av.w;
    Bs[sk + 0][si] = bv.x; Bs[sk + 1][si] = bv.y; Bs[sk + 2][si] = bv.z; Bs[sk + 3][si] = bv.w;
    __syncthreads();
#pragma unroll
    for (int kk = 0; kk < 16; ++kk) {
      const float4 a = *(const float4*)&As[kk][ty * 4];
      const float4 b = *(const float4*)&Bs[kk][tx * 4];
      acc[0][0] += a.x * b.x; acc[0][1] += a.x * b.y; acc[0][2] += a.x * b.z; acc[0][3] += a.x * b.w;
      acc[1][0] += a.y * b.x; acc[1][1] += a.y * b.y; acc[1][2] += a.y * b.z; acc[1][3] += a.y * b.w;
      acc[2][0] += a.z * b.x; acc[2][1] += a.z * b.y; acc[2][2] += a.z * b.z; acc[2][3] += a.z * b.w;
      acc[3][0] += a.w * b.x; acc[3][1] += a.w * b.y; acc[3][2] += a.w * b.z; acc[3][3] += a.w * b.w;
    }
  }
#pragma unroll
  for (int i = 0; i < 4; ++i) {
    const int t = t0 + ty * 4 + i;
#pragma unroll
    for (int j = 0; j < 4; ++j) {
      const int r = r0 + tx * 4 + j;
      const float bias = (r < 2560) ? (bioux[r] + biouh[r]) : (blx[r - 2560] + blh[r - 2560]);
      P[(size_t)t * 3072 + r] = acc[i][j] + bias;
    }
  }
}

// ---------------- persistent recurrent kernel ----------------
// 128 WGs (64/dir). Each WG owns 8 columns; 32 lanes per column.
// Weights: 6 rows x 16 floats/thread = 96 VGPRs, asm-pinned register-resident.
// Relatives: lanes 0..7 of each column-group each own one relative (parallel
// index->gather chains); agg reduced by 3 xor-shuffles. Gates computed on all
// lanes (butterfly leaves dsums in every lane; cstate replicated).
// Sync: 64-bit {h,tag} packets, parity double-buffered, relaxed agent atomics.
__global__ __launch_bounds__(256, 1)
void k_rec(const float* __restrict__ Wiouh, const float* __restrict__ Wlh,
           const float* __restrict__ P, const float* __restrict__ lb,
           const int* __restrict__ rel_fw, const int* __restrict__ dep_fw,
           const unsigned char* __restrict__ mask_fw,
           const int* __restrict__ rel_bw, const int* __restrict__ dep_bw,
           const unsigned char* __restrict__ mask_bw,
           float* __restrict__ Gfw, float* __restrict__ Gbw,
           unsigned long long* rec, float* __restrict__ out)
{
  const int wg  = blockIdx.x;
  const int dir = wg / WPD;
  const int w   = wg % WPD;
  const int tid = threadIdx.x;
  const int grp = tid >> 5;            // 8 column-groups per WG
  const int lane = tid & 31;           // 32 lanes per column
  const int kl = lane & 7;             // owned relative slot (lanes 8..31 duplicate)
  const int m = w * 8 + grp;           // owned h-column
  const int dircol = dir * 512;
  const int* rel = dir ? rel_bw : rel_fw;
  const int* dep = dir ? dep_bw : dep_fw;
  const unsigned char* msk = dir ? mask_bw : mask_fw;
  float* Gbuf = dir ? Gbw : Gfw;

  // ---- weights into registers: 6 rows x 16 cols each, pinned ----
  F4 wreg[6][4];
  {
    const float* rows[6];
#pragma unroll
    for (int rg = 0; rg < 5; ++rg) rows[rg] = Wiouh + (size_t)(rg * 512 + m) * 512;
    rows[5] = Wlh + (size_t)m * 512;
#pragma unroll
    for (int rg = 0; rg < 6; ++rg)
#pragma unroll
      for (int q = 0; q < 4; ++q) {
        wreg[rg][q] = *(const F4*)(rows[rg] + lane * 4 + 128 * q);
        asm volatile("" : "+v"(wreg[rg][q].x), "+v"(wreg[rg][q].y),
                          "+v"(wreg[rg][q].z), "+v"(wreg[rg][q].w));
      }
  }

  __shared__ float hs[2][512];
  hs[0][tid] = 0.0f; hs[0][tid + 256] = 0.0f;

  float cstate = 0.0f;

  // ---- per-lane prefetch for the first step ----
  int jj, mk;
  float Hg, Gg, LBg;
  float p0, p1, p2, p3, p4, p5;
  {
    const int tf = dir ? (S_LEN - 1) : 0;
    const int tb = tf * KREL;
    jj = rel[tb + kl]; mk = (int)msk[tb + kl];
    // first step's relatives are fully masked (reference guarantees); loads are dead but in-bounds
    Hg = out[(size_t)jj * 1024 + dircol + m];
    Gg = Gbuf[(size_t)jj * 512 + m];
    LBg = lb[(size_t)dep[tb + kl] * 512 + m];
    const float* prow = P + (size_t)tf * 3072;
    p0 = prow[m];        p1 = prow[512 + m];  p2 = prow[1024 + m];
    p3 = prow[1536 + m]; p4 = prow[2048 + m]; p5 = prow[2560 + m];
  }
  __syncthreads();

#pragma unroll 1
  for (int s = 0; s < S_LEN; ++s) {
    const int t = dir ? (S_LEN - 1 - s) : s;
    const int tn = dir ? (t - 1) : (t + 1);      // next step's t (valid if s<S_LEN-1)
    const int prevt = dir ? (t + 1) : (t - 1);   // valid only for s>0

    if (s > 0) {
      // ---- joint poll of both packets (one latency when both land together) ----
      const int pb = (((s - 1) & 1) * 2 + dir) * 512;
      unsigned long long v0 = __hip_atomic_load(rec + pb + tid,       __ATOMIC_RELAXED, __HIP_MEMORY_SCOPE_AGENT);
      unsigned long long v1 = __hip_atomic_load(rec + pb + tid + 256, __ATOMIC_RELAXED, __HIP_MEMORY_SCOPE_AGENT);
      for (;;) {
        const bool ok0 = (unsigned)(v0 >> 32) >= (unsigned)s;
        const bool ok1 = (unsigned)(v1 >> 32) >= (unsigned)s;
        if (ok0 && ok1) break;
        if (!ok0) v0 = __hip_atomic_load(rec + pb + tid,       __ATOMIC_RELAXED, __HIP_MEMORY_SCOPE_AGENT);
        if (!ok1) v1 = __hip_atomic_load(rec + pb + tid + 256, __ATOMIC_RELAXED, __HIP_MEMORY_SCOPE_AGENT);
      }
      hs[s & 1][tid]       = __uint_as_float((unsigned)v0);
      hs[s & 1][tid + 256] = __uint_as_float((unsigned)v1);
      __syncthreads();   // the only barrier per step
    }

    // ---- recurrent dots: 6 owned rows x 16 elems/lane, butterfly over 32 lanes ----
    float4 h4[4];
#pragma unroll
    for (int q = 0; q < 4; ++q) h4[q] = *(const float4*)&hs[s & 1][lane * 4 + 128 * q];
    float dsum[6];
#pragma unroll
    for (int rg = 0; rg < 6; ++rg) {
      float a = 0.0f;
#pragma unroll
      for (int q = 0; q < 4; ++q) {
        a += wreg[rg][q].x * h4[q].x;
        a += wreg[rg][q].y * h4[q].y;
        a += wreg[rg][q].z * h4[q].z;
        a += wreg[rg][q].w * h4[q].w;
      }
      a += __shfl_xor(a, 1); a += __shfl_xor(a, 2); a += __shfl_xor(a, 4);
      a += __shfl_xor(a, 8); a += __shfl_xor(a, 16);
      dsum[rg] = a;        // full sum in ALL 32 lanes
    }

    // ---- gates on all lanes (cstate replicated; faithful gate order) ----
    const float iv = sigmf(p0 + dsum[0]);
    const float ov = sigmf(p1 + dsum[1]);
    const float sv = sigmf(p2 + dsum[2]);
    const float fv = sigmf(p3 + dsum[3]);
    const float uv = tanhfast(p4 + dsum[4]);
    cstate = fv * cstate + iv * uv;
    const float hb = ov * tanhfast(cstate);
    const float g = dsum[5];                         // Wlh @ h_prev = G[prevt]

    // ---- per-lane relative summand, reduced over the 8 owned slots ----
    const float gv = (s > 0 && jj == prevt) ? g : Gg;
    float sm = (lane < 8 && mk) ? (sigmf(gv + p5 + LBg) * Hg) : 0.0f;
    sm += __shfl_xor(sm, 1); sm += __shfl_xor(sm, 2); sm += __shfl_xor(sm, 4);
    // lanes 0..7 hold agg (their aligned 8-group = the 8 real summands)
    const float hval = hb + sv * tanhfast(sm);       // valid on lanes 0..7

    if (lane == 0) {
      const unsigned long long pk =
          ((unsigned long long)(unsigned)(s + 1) << 32) | (unsigned long long)__float_as_uint(hval);
      __hip_atomic_store(rec + ((s & 1) * 2 + dir) * 512 + m, pk,
                         __ATOMIC_RELAXED, __HIP_MEMORY_SCOPE_AGENT);
      out[(size_t)t * 1024 + dircol + m] = hval;
      if (s > 0) Gbuf[(size_t)prevt * 512 + m] = g;
    }

    // ---- per-lane prefetch of next step's gathers (parallel dependent chains) ----
    if (s < S_LEN - 1) {
      const int tb = tn * KREL;
      jj = rel[tb + kl]; mk = (int)msk[tb + kl];
      // rows stored this step are patched from registers (loads of them are
      // discarded by the select, so staleness is harmless):
      Hg = (jj == t) ? hval : out[(size_t)jj * 1024 + dircol + m];
      Gg = (s > 0 && jj == prevt) ? g : Gbuf[(size_t)jj * 512 + m];
      // jj==t (G row written next step) is patched at use time (prevt' == t)
      LBg = lb[(size_t)dep[tb + kl] * 512 + m];
      const float* prow = P + (size_t)tn * 3072;
      p0 = prow[m];        p1 = prow[512 + m];  p2 = prow[1024 + m];
      p3 = prow[1536 + m]; p4 = prow[2048 + m]; p5 = prow[2560 + m];
    }
  }
}

__global__ void k_fill(float* __restrict__ o, int n, float v)
{ const int i = blockIdx.x * 256 + threadIdx.x; if (i < n) o[i] = v; }

extern "C" void kernel_launch(void* const* d_in, const int* in_sizes, int n_in,
                              void* d_out, int out_size, void* d_ws, size_t ws_size,
                              hipStream_t stream)
{
  (void)in_sizes; (void)n_in;
  const float* X     = (const float*)d_in[0];
  const float* Wioux = (const float*)d_in[1];
  const float* bioux = (const float*)d_in[2];
  const float* Wiouh = (const float*)d_in[3];
  const float* biouh = (const float*)d_in[4];
  const float* Wlx   = (const float*)d_in[5];
  const float* blx   = (const float*)d_in[6];
  const float* Wlh   = (const float*)d_in[7];
  const float* blh   = (const float*)d_in[8];
  const float* lb    = (const float*)d_in[9];
  const int* rel_fw  = (const int*)d_in[10];
  const int* dep_fw  = (const int*)d_in[11];
  const unsigned char* mask_fw_raw = (const unsigned char*)d_in[12];
  const int* rel_bw  = (const int*)d_in[13];
  const int* dep_bw  = (const int*)d_in[14];
  const unsigned char* mask_bw_raw = (const unsigned char*)d_in[15];
  float* out = (float*)d_out;

  const int nmask = S_LEN * KREL;                  // 65536
  const size_t needP = (size_t)S_LEN * 3072 * 4;   // 96 MB
  const size_t needG = (size_t)S_LEN * 512 * 4;    // 16 MB each
  const size_t need  = 32768 + needP + 2 * needG + 2 * (size_t)nmask;
  if (ws_size < need) {
    k_fill<<<(out_size + 255) / 256, 256, 0, stream>>>(out, out_size, 12345.0f);
    return;
  }
  char* ws = (char*)d_ws;
  unsigned long long* rec = (unsigned long long*)ws;   // [2 buf][2 dir][512] packets
  float* P   = (float*)(ws + 32768);
  float* Gfw = (float*)(ws + 32768 + needP);
  float* Gbw = Gfw + (size_t)S_LEN * 512;
  unsigned char* Mfw = (unsigned char*)(ws + 32768 + needP + 2 * needG);
  unsigned char* Mbw = Mfw + nmask;

  hipMemsetAsync(rec, 0, 16384, stream);   // tags must start at 0 (ws is poisoned 0xAA)
  k_maskcvt<<<64, 256, 0, stream>>>(mask_fw_raw, Mfw, nmask);
  k_maskcvt<<<64, 256, 0, stream>>>(mask_bw_raw, Mbw, nmask);
  dim3 gg(S_LEN / 64, 3072 / 64);
  k_gemm<<<gg, 256, 0, stream>>>(X, Wioux, Wlx, bioux, biouh, blx, blh, P);
  k_rec<<<2 * WPD, 256, 0, stream>>>(Wiouh, Wlh, P, lb, rel_fw, dep_fw, Mfw,
                                     rel_bw, dep_bw, Mbw, Gfw, Gbw, rec, out);
}